// Round 3
// baseline (733.910 us; speedup 1.0000x reference)
//
#include <hip/hip_runtime.h>

#define DD 128

// ---------------- CSR build ----------------

__global__ __launch_bounds__(256) void hist_kernel(const int* __restrict__ src,
                                                   const int* __restrict__ dst,
                                                   int* __restrict__ cnt_out,
                                                   int* __restrict__ cnt_in, int e) {
  int i = blockIdx.x * blockDim.x + threadIdx.x;
  if (i < e) {
    atomicAdd(&cnt_out[src[i]], 1);
    atomicAdd(&cnt_in[dst[i]], 1);
  }
}

// Multi-block scan, phase 1: per-block (2048-elem) sums.
__global__ __launch_bounds__(256) void scan_partial_kernel(const int* __restrict__ cnt,
                                                           int* __restrict__ bsum, int n) {
  __shared__ int ws[4];
  int tid = threadIdx.x;
  int base = blockIdx.x * 2048 + tid * 8;
  int s = 0;
#pragma unroll
  for (int i = 0; i < 8; ++i) {
    int id = base + i;
    if (id < n) s += cnt[id];
  }
#pragma unroll
  for (int d = 32; d; d >>= 1) s += __shfl_xor(s, d, 64);
  int lane = tid & 63, wid = tid >> 6;
  if (lane == 0) ws[wid] = s;
  __syncthreads();
  if (tid == 0) bsum[blockIdx.x] = ws[0] + ws[1] + ws[2] + ws[3];
}

// Phase 2: exclusive scan of block sums (single wave, chunks of 64).
__global__ __launch_bounds__(64) void scan_bsum_kernel(int* __restrict__ bsum, int nb) {
  int lane = threadIdx.x;
  int run = 0;
  for (int base = 0; base < nb; base += 64) {
    int id = base + lane;
    int v = (id < nb) ? bsum[id] : 0;
    int sc = v;
#pragma unroll
    for (int d = 1; d < 64; d <<= 1) {
      int t = __shfl_up(sc, d, 64);
      if (lane >= d) sc += t;
    }
    if (id < nb) bsum[id] = run + sc - v;
    run += __shfl(sc, 63, 64);
  }
}

// Phase 3: final scatter of exclusive scan -> row_ptr, cursor.
__global__ __launch_bounds__(256) void scan_final_kernel(const int* __restrict__ cnt,
                                                         const int* __restrict__ bsum,
                                                         int* __restrict__ row_ptr,
                                                         int* __restrict__ cursor,
                                                         int n, int e_total) {
  __shared__ int ws[4];
  int tid = threadIdx.x, lane = tid & 63, wid = tid >> 6;
  int base = blockIdx.x * 2048 + tid * 8;
  int v[8];
  int s = 0;
#pragma unroll
  for (int i = 0; i < 8; ++i) {
    int id = base + i;
    v[i] = (id < n) ? cnt[id] : 0;
    s += v[i];
  }
  int sc = s;
#pragma unroll
  for (int d = 1; d < 64; d <<= 1) {
    int t = __shfl_up(sc, d, 64);
    if (lane >= d) sc += t;
  }
  if (lane == 63) ws[wid] = sc;
  __syncthreads();
  int woff = 0;
  for (int w = 0; w < wid; ++w) woff += ws[w];
  int off = bsum[blockIdx.x] + woff + (sc - s);
#pragma unroll
  for (int i = 0; i < 8; ++i) {
    int id = base + i;
    if (id < n) {
      row_ptr[id] = off;
      cursor[id] = off;
      off += v[i];
    }
  }
  if (blockIdx.x == 0 && tid == 0) row_ptr[n] = e_total;
}

__global__ __launch_bounds__(256) void norm_kernel(const int* __restrict__ cnt_out,
                                                   const int* __restrict__ cnt_in,
                                                   float* __restrict__ norm_src,
                                                   float* __restrict__ norm_dst, int n) {
  int i = blockIdx.x * blockDim.x + threadIdx.x;
  if (i < n) {
    int co = cnt_out[i]; if (co < 1) co = 1;
    int ci = cnt_in[i]; if (ci < 1) ci = 1;
    norm_src[i] = 1.0f / sqrtf((float)co);
    norm_dst[i] = 1.0f / sqrtf((float)ci);
  }
}

__global__ __launch_bounds__(256) void fill_kernel(const int* __restrict__ src,
                                                   const int* __restrict__ dst,
                                                   int* __restrict__ cursor,
                                                   int* __restrict__ adj, int e) {
  int i = blockIdx.x * blockDim.x + threadIdx.x;
  if (i < e) {
    int p = atomicAdd(&cursor[dst[i]], 1);
    adj[p] = src[i];
  }
}

// ---------------- per-layer kernels ----------------

// One wave per dst node. readfirstlane forces node/beg/end into SGPRs so adj
// and norm_src loads are scalar; 8 row-gathers (512B each) in flight per wave.
__global__ __launch_bounds__(256) void agg_kernel(const float* __restrict__ h,
                                                  const int* __restrict__ adj,
                                                  const int* __restrict__ row_ptr,
                                                  const float* __restrict__ norm_src,
                                                  const float* __restrict__ norm_dst,
                                                  float* __restrict__ out, int n) {
  int node = __builtin_amdgcn_readfirstlane(blockIdx.x * 4 + (threadIdx.x >> 6));
  int lane = threadIdx.x & 63;
  if (node >= n) return;
  int beg = row_ptr[node];
  int end = row_ptr[node + 1];
  float accx = 0.f, accy = 0.f;
  const float* hp = h + lane * 2;
  int j = beg;
  for (; j + 8 <= end; j += 8) {
    int s0 = adj[j + 0], s1 = adj[j + 1], s2 = adj[j + 2], s3 = adj[j + 3];
    int s4 = adj[j + 4], s5 = adj[j + 5], s6 = adj[j + 6], s7 = adj[j + 7];
    float w0 = norm_src[s0], w1 = norm_src[s1], w2 = norm_src[s2], w3 = norm_src[s3];
    float w4 = norm_src[s4], w5 = norm_src[s5], w6 = norm_src[s6], w7 = norm_src[s7];
    float2 v0 = *(const float2*)(hp + (size_t)s0 * DD);
    float2 v1 = *(const float2*)(hp + (size_t)s1 * DD);
    float2 v2 = *(const float2*)(hp + (size_t)s2 * DD);
    float2 v3 = *(const float2*)(hp + (size_t)s3 * DD);
    float2 v4 = *(const float2*)(hp + (size_t)s4 * DD);
    float2 v5 = *(const float2*)(hp + (size_t)s5 * DD);
    float2 v6 = *(const float2*)(hp + (size_t)s6 * DD);
    float2 v7 = *(const float2*)(hp + (size_t)s7 * DD);
    accx = fmaf(w0, v0.x, accx); accy = fmaf(w0, v0.y, accy);
    accx = fmaf(w1, v1.x, accx); accy = fmaf(w1, v1.y, accy);
    accx = fmaf(w2, v2.x, accx); accy = fmaf(w2, v2.y, accy);
    accx = fmaf(w3, v3.x, accx); accy = fmaf(w3, v3.y, accy);
    accx = fmaf(w4, v4.x, accx); accy = fmaf(w4, v4.y, accy);
    accx = fmaf(w5, v5.x, accx); accy = fmaf(w5, v5.y, accy);
    accx = fmaf(w6, v6.x, accx); accy = fmaf(w6, v6.y, accy);
    accx = fmaf(w7, v7.x, accx); accy = fmaf(w7, v7.y, accy);
  }
  for (; j < end; ++j) {
    int s0 = adj[j];
    float w0 = norm_src[s0];
    float2 v0 = *(const float2*)(hp + (size_t)s0 * DD);
    accx = fmaf(w0, v0.x, accx);
    accy = fmaf(w0, v0.y, accy);
  }
  float nd = norm_dst[node];
  *(float2*)(out + (size_t)node * DD + lane * 2) =
      make_float2(accx * nd, accy * nd);
}

// In-place X[r,:] = relu(X[r,:] @ W + b), 128x128 tile, both operands in LDS.
// Xs: float4-swizzled (c4 ^ ((r>>3)&7)) -> conflict-free row-varying reads.
// WsT: W transposed [c][k], k4-swizzled by (c&7); thread cols tx+16j -> 2-way max.
__global__ __launch_bounds__(256, 1) void gemm_relu_kernel(float* __restrict__ X,
                                                           const float* __restrict__ W,
                                                           const float* __restrict__ bias,
                                                           int n) {
  __shared__ float4 Xs4[128 * 32];   // 64 KB
  __shared__ float WsT[128 * 128];   // 64 KB
  int tid = threadIdx.x;
  int row0 = blockIdx.x * 128;
  const float4* X4 = (const float4*)X;
  const float4* W4 = (const float4*)W;
#pragma unroll
  for (int i = 0; i < 16; ++i) {
    int f4 = tid + 256 * i;
    int r = f4 >> 5, c4 = f4 & 31;
    float4 v = make_float4(0.f, 0.f, 0.f, 0.f);
    if (row0 + r < n) v = X4[(size_t)(row0 + r) * 32 + c4];
    Xs4[r * 32 + (c4 ^ ((r >> 3) & 7))] = v;
  }
#pragma unroll
  for (int i = 0; i < 16; ++i) {
    int f4 = tid + 256 * i;
    int k = f4 >> 5, c4 = f4 & 31;
    float4 wv = W4[(size_t)k * 32 + c4];
    int k4 = k >> 2, km = k & 3;
    int c0 = c4 * 4;
    WsT[(c0 + 0) * 128 + ((k4 ^ ((c0 + 0) & 7)) << 2) + km] = wv.x;
    WsT[(c0 + 1) * 128 + ((k4 ^ ((c0 + 1) & 7)) << 2) + km] = wv.y;
    WsT[(c0 + 2) * 128 + ((k4 ^ ((c0 + 2) & 7)) << 2) + km] = wv.z;
    WsT[(c0 + 3) * 128 + ((k4 ^ ((c0 + 3) & 7)) << 2) + km] = wv.w;
  }
  __syncthreads();
  int tx = tid & 15, ty = tid >> 4;
  const float4* WsT4 = (const float4*)WsT;
  int cxor = tx & 7;
  float acc[8][8] = {};
#pragma unroll 2
  for (int k4 = 0; k4 < 32; ++k4) {
    float4 xv[8], wv[8];
#pragma unroll
    for (int i = 0; i < 8; ++i) {
      int r = ty * 8 + i;
      xv[i] = Xs4[r * 32 + (k4 ^ ((r >> 3) & 7))];
    }
#pragma unroll
    for (int j = 0; j < 8; ++j) {
      int c = tx + 16 * j;
      wv[j] = WsT4[c * 32 + (k4 ^ cxor)];
    }
#pragma unroll
    for (int i = 0; i < 8; ++i)
#pragma unroll
      for (int j = 0; j < 8; ++j) {
        acc[i][j] = fmaf(xv[i].x, wv[j].x, acc[i][j]);
        acc[i][j] = fmaf(xv[i].y, wv[j].y, acc[i][j]);
        acc[i][j] = fmaf(xv[i].z, wv[j].z, acc[i][j]);
        acc[i][j] = fmaf(xv[i].w, wv[j].w, acc[i][j]);
      }
  }
  float bv[8];
#pragma unroll
  for (int j = 0; j < 8; ++j) bv[j] = bias[tx + 16 * j];
  __syncthreads();
  float* Xsf = (float*)Xs4;
#pragma unroll
  for (int i = 0; i < 8; ++i)
#pragma unroll
    for (int j = 0; j < 8; ++j)
      Xsf[(ty * 8 + i) * 128 + tx + 16 * j] = fmaxf(acc[i][j] + bv[j], 0.f);
  __syncthreads();
  float4* Xo4 = (float4*)X;
#pragma unroll
  for (int i = 0; i < 16; ++i) {
    int f4 = tid + 256 * i;
    int r = f4 >> 5, c4 = f4 & 31;
    if (row0 + r < n) Xo4[(size_t)(row0 + r) * 32 + c4] = Xs4[r * 32 + c4];
  }
}

// ---------------- launch ----------------

extern "C" void kernel_launch(void* const* d_in, const int* in_sizes, int n_in,
                              void* d_out, int out_size, void* d_ws, size_t ws_size,
                              hipStream_t stream) {
  const float* feat = (const float*)d_in[0];
  const int* src = (const int*)d_in[1];
  const int* dst = (const int*)d_in[2];
  const float* W = (const float*)d_in[3];
  const float* b = (const float*)d_in[4];
  const int N = in_sizes[0] / DD;
  const int E = in_sizes[1];
  const int L = in_sizes[3] / (DD * DD);

  char* p = (char*)d_ws;
  auto alloc = [&](size_t bytes) {
    void* r = (void*)p;
    p += (bytes + 255) & ~(size_t)255;
    return r;
  };
  int* cnt_in = (int*)alloc((size_t)N * 4);
  int* cnt_out = (int*)alloc((size_t)N * 4);
  int* row_ptr = (int*)alloc(((size_t)N + 1) * 4);
  int* cursor = (int*)alloc((size_t)N * 4);
  int* adj = (int*)alloc((size_t)E * 4);
  float* norm_src = (float*)alloc((size_t)N * 4);
  float* norm_dst = (float*)alloc((size_t)N * 4);
  int* bsum = (int*)alloc(((size_t)N / 2048 + 2) * 4);
  float* hbuf = (float*)alloc((size_t)N * DD * 4);

  const int nb = (N + 2047) / 2048;

  hipMemsetAsync(cnt_in, 0, (size_t)N * 4, stream);
  hipMemsetAsync(cnt_out, 0, (size_t)N * 4, stream);
  hist_kernel<<<(E + 255) / 256, 256, 0, stream>>>(src, dst, cnt_out, cnt_in, E);
  scan_partial_kernel<<<nb, 256, 0, stream>>>(cnt_in, bsum, N);
  scan_bsum_kernel<<<1, 64, 0, stream>>>(bsum, nb);
  scan_final_kernel<<<nb, 256, 0, stream>>>(cnt_in, bsum, row_ptr, cursor, N, E);
  norm_kernel<<<(N + 255) / 256, 256, 0, stream>>>(cnt_out, cnt_in, norm_src, norm_dst, N);
  fill_kernel<<<(E + 255) / 256, 256, 0, stream>>>(src, dst, cursor, adj, E);

  float* out_f = (float*)d_out;
  for (int l = 0; l < L; ++l) {
    float* ho = (((L - 1 - l) % 2) == 0) ? out_f : hbuf;
    const float* hi = (l == 0) ? feat
                               : ((((L - l) % 2) == 0) ? (const float*)out_f
                                                       : (const float*)hbuf);
    agg_kernel<<<(N + 3) / 4, 256, 0, stream>>>(hi, adj, row_ptr, norm_src, norm_dst,
                                                ho, N);
    gemm_relu_kernel<<<(N + 127) / 128, 256, 0, stream>>>(
        ho, W + (size_t)l * DD * DD, b + (size_t)l * DD, N);
  }
}

// Round 4
// 645.676 us; speedup vs baseline: 1.1367x; 1.1367x over previous
//
#include <hip/hip_runtime.h>

#define DD 128

// ---------------- CSR build ----------------

__global__ __launch_bounds__(256) void hist_kernel(const int* __restrict__ src,
                                                   const int* __restrict__ dst,
                                                   int* __restrict__ cnt_out,
                                                   int* __restrict__ cnt_in, int e) {
  int i = blockIdx.x * blockDim.x + threadIdx.x;
  if (i < e) {
    atomicAdd(&cnt_out[src[i]], 1);
    atomicAdd(&cnt_in[dst[i]], 1);
  }
}

// Multi-block scan, phase 1: per-block (2048-elem) sums.
__global__ __launch_bounds__(256) void scan_partial_kernel(const int* __restrict__ cnt,
                                                           int* __restrict__ bsum, int n) {
  __shared__ int ws[4];
  int tid = threadIdx.x;
  int base = blockIdx.x * 2048 + tid * 8;
  int s = 0;
#pragma unroll
  for (int i = 0; i < 8; ++i) {
    int id = base + i;
    if (id < n) s += cnt[id];
  }
#pragma unroll
  for (int d = 32; d; d >>= 1) s += __shfl_xor(s, d, 64);
  int lane = tid & 63, wid = tid >> 6;
  if (lane == 0) ws[wid] = s;
  __syncthreads();
  if (tid == 0) bsum[blockIdx.x] = ws[0] + ws[1] + ws[2] + ws[3];
}

// Phase 2: exclusive scan of block sums (single wave, chunks of 64).
__global__ __launch_bounds__(64) void scan_bsum_kernel(int* __restrict__ bsum, int nb) {
  int lane = threadIdx.x;
  int run = 0;
  for (int base = 0; base < nb; base += 64) {
    int id = base + lane;
    int v = (id < nb) ? bsum[id] : 0;
    int sc = v;
#pragma unroll
    for (int d = 1; d < 64; d <<= 1) {
      int t = __shfl_up(sc, d, 64);
      if (lane >= d) sc += t;
    }
    if (id < nb) bsum[id] = run + sc - v;
    run += __shfl(sc, 63, 64);
  }
}

// Phase 3: final scatter of exclusive scan -> row_ptr, cursor.
__global__ __launch_bounds__(256) void scan_final_kernel(const int* __restrict__ cnt,
                                                         const int* __restrict__ bsum,
                                                         int* __restrict__ row_ptr,
                                                         int* __restrict__ cursor,
                                                         int n, int e_total) {
  __shared__ int ws[4];
  int tid = threadIdx.x, lane = tid & 63, wid = tid >> 6;
  int base = blockIdx.x * 2048 + tid * 8;
  int v[8];
  int s = 0;
#pragma unroll
  for (int i = 0; i < 8; ++i) {
    int id = base + i;
    v[i] = (id < n) ? cnt[id] : 0;
    s += v[i];
  }
  int sc = s;
#pragma unroll
  for (int d = 1; d < 64; d <<= 1) {
    int t = __shfl_up(sc, d, 64);
    if (lane >= d) sc += t;
  }
  if (lane == 63) ws[wid] = sc;
  __syncthreads();
  int woff = 0;
  for (int w = 0; w < wid; ++w) woff += ws[w];
  int off = bsum[blockIdx.x] + woff + (sc - s);
#pragma unroll
  for (int i = 0; i < 8; ++i) {
    int id = base + i;
    if (id < n) {
      row_ptr[id] = off;
      cursor[id] = off;
      off += v[i];
    }
  }
  if (blockIdx.x == 0 && tid == 0) row_ptr[n] = e_total;
}

__global__ __launch_bounds__(256) void norm_kernel(const int* __restrict__ cnt_out,
                                                   const int* __restrict__ cnt_in,
                                                   float* __restrict__ norm_src,
                                                   float* __restrict__ norm_dst, int n) {
  int i = blockIdx.x * blockDim.x + threadIdx.x;
  if (i < n) {
    int co = cnt_out[i]; if (co < 1) co = 1;
    int ci = cnt_in[i]; if (ci < 1) ci = 1;
    norm_src[i] = 1.0f / sqrtf((float)co);
    norm_dst[i] = 1.0f / sqrtf((float)ci);
  }
}

__global__ __launch_bounds__(256) void fill_kernel(const int* __restrict__ src,
                                                   const int* __restrict__ dst,
                                                   int* __restrict__ cursor,
                                                   int* __restrict__ adj, int e) {
  int i = blockIdx.x * blockDim.x + threadIdx.x;
  if (i < e) {
    int p = atomicAdd(&cursor[dst[i]], 1);
    adj[p] = src[i];
  }
}

// g[i,:] = feat[i,:] * norm_src[i]
__global__ __launch_bounds__(256) void prescale_kernel(const float* __restrict__ feat,
                                                       const float* __restrict__ ns,
                                                       float* __restrict__ g, int n) {
  int i = blockIdx.x * 256 + threadIdx.x;  // float4 index
  if (i < n * 32) {
    float4 v = ((const float4*)feat)[i];
    float s = ns[i >> 5];
    v.x *= s; v.y *= s; v.z *= s; v.w *= s;
    ((float4*)g)[i] = v;
  }
}

// ---------------- per-layer kernels ----------------

// One wave per dst node: T[v,:] = sum_{s in adj[v]} g[s,:]   (no weights!)
// Pair-packed: lanes 0-31 gather edge 2j's row (float4/lane), lanes 32-63
// edge 2j+1's row. 4 pairs (8 edges) in flight. shfl_xor(32) fold at end.
__global__ __launch_bounds__(256) void agg_kernel(const float* __restrict__ g,
                                                  const int* __restrict__ adj,
                                                  const int* __restrict__ row_ptr,
                                                  float* __restrict__ T, int n) {
  int node = __builtin_amdgcn_readfirstlane(blockIdx.x * 4 + (threadIdx.x >> 6));
  if (node >= n) return;
  int lane = threadIdx.x & 63;
  int m = lane & 31;
  int half = lane >> 5;
  int beg = row_ptr[node];
  int end = row_ptr[node + 1];
  const float4* g4 = (const float4*)g;
  float ax = 0.f, ay = 0.f, az = 0.f, aw = 0.f;
  int j = beg;
  for (; j + 8 <= end; j += 8) {
    int s0 = adj[j + 0], s1 = adj[j + 1], s2 = adj[j + 2], s3 = adj[j + 3];
    int s4 = adj[j + 4], s5 = adj[j + 5], s6 = adj[j + 6], s7 = adj[j + 7];
    int a0 = half ? s1 : s0;
    int a1 = half ? s3 : s2;
    int a2 = half ? s5 : s4;
    int a3 = half ? s7 : s6;
    float4 v0 = g4[(size_t)a0 * 32 + m];
    float4 v1 = g4[(size_t)a1 * 32 + m];
    float4 v2 = g4[(size_t)a2 * 32 + m];
    float4 v3 = g4[(size_t)a3 * 32 + m];
    ax += v0.x + v1.x + v2.x + v3.x;
    ay += v0.y + v1.y + v2.y + v3.y;
    az += v0.z + v1.z + v2.z + v3.z;
    aw += v0.w + v1.w + v2.w + v3.w;
  }
  for (; j + 2 <= end; j += 2) {
    int s0 = adj[j], s1 = adj[j + 1];
    int a = half ? s1 : s0;
    float4 v = g4[(size_t)a * 32 + m];
    ax += v.x; ay += v.y; az += v.z; aw += v.w;
  }
  if (j < end) {
    int s0 = adj[j];
    if (half == 0) {
      float4 v = g4[(size_t)s0 * 32 + m];
      ax += v.x; ay += v.y; az += v.z; aw += v.w;
    }
  }
  ax += __shfl_xor(ax, 32, 64);
  ay += __shfl_xor(ay, 32, 64);
  az += __shfl_xor(az, 32, 64);
  aw += __shfl_xor(aw, 32, 64);
  if (half == 0)
    ((float4*)T)[(size_t)node * 32 + m] = make_float4(ax, ay, az, aw);
}

// Xout[r,:] = relu((Xin[r,:]*nd[r]) @ W + b) * (last ? 1 : ns[r])
// 64-row tile in LDS (32 KB, 5 blocks/CU), 256 thr, thread = 8 rows x 4 cols.
__global__ __launch_bounds__(256) void gemm_relu_kernel(const float* __restrict__ Xin,
                                                        float* __restrict__ Xout,
                                                        const float* __restrict__ W,
                                                        const float* __restrict__ bias,
                                                        const float* __restrict__ nd,
                                                        const float* __restrict__ ns,
                                                        int n, int last) {
  __shared__ float Xs[64][DD];
  int tid = threadIdx.x;
  int row0 = blockIdx.x * 64;
  // load 64x128 tile scaled by nd: 2048 float4, 8 per thread, coalesced
#pragma unroll
  for (int i = 0; i < 8; ++i) {
    int f4 = tid + 256 * i;
    int r = f4 >> 5, c4 = f4 & 31;
    float4 v = make_float4(0.f, 0.f, 0.f, 0.f);
    if (row0 + r < n) {
      v = *(const float4*)(Xin + (size_t)(row0 + r) * DD + c4 * 4);
      float s = nd[row0 + r];
      v.x *= s; v.y *= s; v.z *= s; v.w *= s;
    }
    *(float4*)&Xs[r][c4 * 4] = v;
  }
  __syncthreads();
  int tx = tid & 31;   // col group: cols tx*4..tx*4+3
  int ty = tid >> 5;   // row group: rows ty*8..ty*8+7
  float acc[8][4] = {};
  const float4* wp0 = (const float4*)W + tx;
  for (int k4 = 0; k4 < DD / 4; ++k4) {
    const float4* wp = wp0 + (size_t)k4 * 4 * 32;
    float4 w0 = wp[0];
    float4 w1 = wp[32];
    float4 w2 = wp[64];
    float4 w3 = wp[96];
#pragma unroll
    for (int i = 0; i < 8; ++i) {
      float4 x = *(const float4*)&Xs[ty * 8 + i][k4 * 4];
      acc[i][0] = fmaf(x.x, w0.x, acc[i][0]);
      acc[i][1] = fmaf(x.x, w0.y, acc[i][1]);
      acc[i][2] = fmaf(x.x, w0.z, acc[i][2]);
      acc[i][3] = fmaf(x.x, w0.w, acc[i][3]);
      acc[i][0] = fmaf(x.y, w1.x, acc[i][0]);
      acc[i][1] = fmaf(x.y, w1.y, acc[i][1]);
      acc[i][2] = fmaf(x.y, w1.z, acc[i][2]);
      acc[i][3] = fmaf(x.y, w1.w, acc[i][3]);
      acc[i][0] = fmaf(x.z, w2.x, acc[i][0]);
      acc[i][1] = fmaf(x.z, w2.y, acc[i][1]);
      acc[i][2] = fmaf(x.z, w2.z, acc[i][2]);
      acc[i][3] = fmaf(x.z, w2.w, acc[i][3]);
      acc[i][0] = fmaf(x.w, w3.x, acc[i][0]);
      acc[i][1] = fmaf(x.w, w3.y, acc[i][1]);
      acc[i][2] = fmaf(x.w, w3.z, acc[i][2]);
      acc[i][3] = fmaf(x.w, w3.w, acc[i][3]);
    }
  }
  float4 bv = *(const float4*)(bias + tx * 4);
#pragma unroll
  for (int i = 0; i < 8; ++i) {
    int r = row0 + ty * 8 + i;
    if (r < n) {
      float4 o;
      o.x = fmaxf(acc[i][0] + bv.x, 0.f);
      o.y = fmaxf(acc[i][1] + bv.y, 0.f);
      o.z = fmaxf(acc[i][2] + bv.z, 0.f);
      o.w = fmaxf(acc[i][3] + bv.w, 0.f);
      if (!last) {
        float s = ns[r];
        o.x *= s; o.y *= s; o.z *= s; o.w *= s;
      }
      *(float4*)(Xout + (size_t)r * DD + tx * 4) = o;
    }
  }
}

// ---------------- launch ----------------

extern "C" void kernel_launch(void* const* d_in, const int* in_sizes, int n_in,
                              void* d_out, int out_size, void* d_ws, size_t ws_size,
                              hipStream_t stream) {
  const float* feat = (const float*)d_in[0];
  const int* src = (const int*)d_in[1];
  const int* dst = (const int*)d_in[2];
  const float* W = (const float*)d_in[3];
  const float* b = (const float*)d_in[4];
  const int N = in_sizes[0] / DD;
  const int E = in_sizes[1];
  const int L = in_sizes[3] / (DD * DD);

  char* p = (char*)d_ws;
  auto alloc = [&](size_t bytes) {
    void* r = (void*)p;
    p += (bytes + 255) & ~(size_t)255;
    return r;
  };
  int* cnt_in = (int*)alloc((size_t)N * 4);
  int* cnt_out = (int*)alloc((size_t)N * 4);
  int* row_ptr = (int*)alloc(((size_t)N + 1) * 4);
  int* cursor = (int*)alloc((size_t)N * 4);
  int* adj = (int*)alloc((size_t)E * 4);
  float* norm_src = (float*)alloc((size_t)N * 4);
  float* norm_dst = (float*)alloc((size_t)N * 4);
  int* bsum = (int*)alloc(((size_t)N / 2048 + 2) * 4);
  float* hbuf = (float*)alloc((size_t)N * DD * 4);

  const int nb = (N + 2047) / 2048;

  hipMemsetAsync(cnt_in, 0, (size_t)N * 4, stream);
  hipMemsetAsync(cnt_out, 0, (size_t)N * 4, stream);
  hist_kernel<<<(E + 255) / 256, 256, 0, stream>>>(src, dst, cnt_out, cnt_in, E);
  scan_partial_kernel<<<nb, 256, 0, stream>>>(cnt_in, bsum, N);
  scan_bsum_kernel<<<1, 64, 0, stream>>>(bsum, nb);
  scan_final_kernel<<<nb, 256, 0, stream>>>(cnt_in, bsum, row_ptr, cursor, N, E);
  norm_kernel<<<(N + 255) / 256, 256, 0, stream>>>(cnt_out, cnt_in, norm_src, norm_dst, N);
  fill_kernel<<<(E + 255) / 256, 256, 0, stream>>>(src, dst, cursor, adj, E);

  float* out_f = (float*)d_out;
  // g lives in d_out; T (agg output) in hbuf; gemm writes back to d_out.
  prescale_kernel<<<(N * 32 + 255) / 256, 256, 0, stream>>>(feat, norm_src, out_f, N);
  for (int l = 0; l < L; ++l) {
    agg_kernel<<<(N + 3) / 4, 256, 0, stream>>>(out_f, adj, row_ptr, hbuf, N);
    gemm_relu_kernel<<<(N + 63) / 64, 256, 0, stream>>>(
        hbuf, out_f, W + (size_t)l * DD * DD, b + (size_t)l * DD, norm_dst,
        norm_src, N, (l == L - 1) ? 1 : 0);
  }
}